// Round 6
// baseline (306.064 us; speedup 1.0000x reference)
//
#include <hip/hip_runtime.h>
#include <hip/hip_bf16.h>

typedef __bf16 bf16;
typedef __bf16 bf16x8 __attribute__((ext_vector_type(8)));
typedef float f32x4 __attribute__((ext_vector_type(4)));

#define MFMA16(a, b, c) __builtin_amdgcn_mfma_f32_16x16x32_bf16((a), (b), (c), 0, 0, 0)

// Problem: B=2, L=4096, D=1024, H=8, Hd=128, CHUNK=64, NCHUNK=64
// gamma_h = 1 - 2^(-5-h).  Inputs fp32, OUTPUT fp32.

// async 16B global->LDS (gfx950). LDS dest is wave-uniform base + lane*16.
__device__ __forceinline__ void g2l16(const bf16* g, bf16* l) {
  __builtin_amdgcn_global_load_lds(
      (const __attribute__((address_space(1))) void*)g,
      (__attribute__((address_space(3))) void*)l, 16, 0, 0);
}

// Transpose-safe LDS index, stride-72 rows (bf16).
__device__ __forceinline__ int swz72(int row, int c) {
  return row * 72 + (c & 7) + ((((c >> 3) ^ (row >> 3)) & 7) << 3);
}

// ---------------------------------------------------------------------------
// prep: fused {fp32->bf16 convert of X} + {transpose+cvt of the 4 weights}.
// ---------------------------------------------------------------------------
__global__ __launch_bounds__(256) void prep(
    const float* __restrict__ X, const float* __restrict__ Wq,
    const float* __restrict__ Wk, const float* __restrict__ Wv,
    const float* __restrict__ Wo, bf16* __restrict__ Xb,
    bf16* __restrict__ Wt) {
  __shared__ bf16 t[64 * 72];
  const int tid = threadIdx.x;
  if (blockIdx.x < 4096) {
    const size_t i = ((size_t)blockIdx.x * 256 + tid) * 8;
    float4 a = *(const float4*)&X[i];
    float4 b = *(const float4*)&X[i + 4];
    union { bf16 h[8]; uint4 u; } p;
    p.h[0] = (bf16)a.x; p.h[1] = (bf16)a.y; p.h[2] = (bf16)a.z; p.h[3] = (bf16)a.w;
    p.h[4] = (bf16)b.x; p.h[5] = (bf16)b.y; p.h[6] = (bf16)b.z; p.h[7] = (bf16)b.w;
    *(uint4*)&Xb[i] = p.u;
    return;
  }
  const int bid2 = blockIdx.x - 4096;          // 0..1023
  const int bx = bid2 & 15, by = (bid2 >> 4) & 15, bz = bid2 >> 8;
  const float* src = (bz == 0) ? Wq : (bz == 1) ? Wk : (bz == 2) ? Wv : Wo;
  bf16* dst = Wt + (size_t)bz * 1024 * 1024;
  const int k0 = bx * 64, n0 = by * 64;
#pragma unroll
  for (int s = 0; s < 4; ++s) {
    int u = tid + s * 256;          // 0..1023
    int r = u >> 4, c4 = (u & 15) * 4;
    float4 f = *(const float4*)&src[(size_t)(k0 + r) * 1024 + n0 + c4];
    t[r * 72 + c4 + 0] = (bf16)f.x;
    t[r * 72 + c4 + 1] = (bf16)f.y;
    t[r * 72 + c4 + 2] = (bf16)f.z;
    t[r * 72 + c4 + 3] = (bf16)f.w;
  }
  __syncthreads();
#pragma unroll
  for (int s = 0; s < 2; ++s) {
    int u = tid + s * 256;
    int r = u >> 3, cc = u & 7;     // output row n0+r, k-chunk cc
    union { bf16 h[8]; uint4 u4; } pk;
#pragma unroll
    for (int j = 0; j < 8; ++j) pk.h[j] = t[(cc * 8 + j) * 72 + r];
    *(uint4*)&dst[(size_t)(n0 + r) * 1024 + k0 + cc * 8] = pk.u4;
  }
}

// ---------------------------------------------------------------------------
// GEMM: C = alpha * (A @ Bt^T).  A: M x 1024 bf16 row-major,
// Bt: 1024 x 1024 bf16 = B^T row-major, C: M x 1024 (TC = bf16 or fp32).
// 128x128 tile, BK=64, 4 waves. global_load_lds(16B) staging with XOR-swizzle.
// PROVEN structure (858 TF here).  QKV fused as gridDim.z=3 (the 3-launch
// split cost +15 us in round 5 — lost inter-slice overlap).
// ---------------------------------------------------------------------------
template <typename TC, int QKV>
__global__ __launch_bounds__(256) void gemm_lds(
    const bf16* __restrict__ A, const bf16* __restrict__ Bt,
    TC* __restrict__ C, float alpha) {
  __shared__ bf16 lA[128 * 64];
  __shared__ bf16 lB[128 * 64];
  const int m0 = blockIdx.x * 128, n0 = blockIdx.y * 128;
  if (QKV) {
    Bt += (size_t)blockIdx.z * 1024 * 1024;
    C += (size_t)blockIdx.z * 8192 * 1024;
    if (blockIdx.z != 0) alpha = 1.0f;
  }
  const int tid = threadIdx.x;
  const int w = tid >> 6, lane = tid & 63, lr = lane & 15, quad = lane >> 4;
  const int wm = w >> 1, wn = w & 1;

  const int srow = w * 32 + (lane >> 3);              // row for issue 0
  const int clog = (lane & 7) ^ ((lane >> 3) & 7);    // swizzled 16B chunk
  const bf16* gA = A + (size_t)(m0 + srow) * 1024 + clog * 8;
  const bf16* gB = Bt + (size_t)(n0 + srow) * 1024 + clog * 8;

  f32x4 acc[4][4] = {};

  for (int it = 0; it < 16; ++it) {
    const int k0 = it * 64;
#pragma unroll
    for (int is = 0; is < 4; ++is) {
      g2l16(gA + (size_t)is * 8 * 1024 + k0, &lA[(w * 32 + is * 8) * 64]);
      g2l16(gB + (size_t)is * 8 * 1024 + k0, &lB[(w * 32 + is * 8) * 64]);
    }
    __syncthreads();
#pragma unroll
    for (int kk = 0; kk < 2; ++kk) {
      bf16x8 af[4], bfv[4];
#pragma unroll
      for (int i = 0; i < 4; ++i) {
        const int m = wm * 64 + i * 16 + lr;
        af[i] = *(bf16x8*)&lA[m * 64 + (((kk * 4 + quad) ^ (lr & 7)) * 8)];
      }
#pragma unroll
      for (int j = 0; j < 4; ++j) {
        const int n = wn * 64 + j * 16 + lr;
        bfv[j] = *(bf16x8*)&lB[n * 64 + (((kk * 4 + quad) ^ (lr & 7)) * 8)];
      }
#pragma unroll
      for (int i = 0; i < 4; ++i)
#pragma unroll
        for (int j = 0; j < 4; ++j)
          acc[i][j] = MFMA16(af[i], bfv[j], acc[i][j]);
    }
    __syncthreads();
  }
#pragma unroll
  for (int i = 0; i < 4; ++i) {
#pragma unroll
    for (int j = 0; j < 4; ++j) {
      const int row = m0 + wm * 64 + i * 16 + quad * 4;
      const int col = n0 + wn * 64 + j * 16 + lr;
#pragma unroll
      for (int r = 0; r < 4; ++r)
        C[(size_t)(row + r) * 1024 + col] = (TC)(acc[i][j][r] * alpha);
    }
  }
}

// ---------------------------------------------------------------------------
// FUSED Phase A+B: chunk_kv + scan_state in one kernel.
// The decay recurrence S <- gamma^64 * S + T_n is elementwise in (dk,dv), so
// one block owns a (bh, dv-half) slice and carries S in fp32 REGISTERS across
// all 64 chunks.  T_n is never materialized (saves 64 MB HBM round-trip, one
// launch, and one bf16 rounding of T_n).
// Grid 32 = 16 bh x 2 dv-halves, 512 threads (8 waves).  Per chunk n:
//   stage k (decay-folded) + v-half -> LDS[n&1] (dbuf, reg-prefetched),
//   1 barrier, 8 MFMA/wave -> T-slice, write Sprev (bf16) to Tb, update S.
// Tb keeps the chunk_out-expected layout: Tb + g*16384, [dv][dk], g=bh*64+n.
// ---------------------------------------------------------------------------
__global__ __launch_bounds__(512) void chunk_kv_scan(
    const bf16* __restrict__ kb, const bf16* __restrict__ vb,
    bf16* __restrict__ Tb) {
  __shared__ bf16 lK[2][128 * 72];  // [dk][c], decay folded, swizzled
  __shared__ bf16 lV[2][64 * 72];   // [dv-local][c], swizzled
  const int bh = blockIdx.x >> 1, half = blockIdx.x & 1;
  const int b = bh >> 3, h = bh & 7, dv0 = half * 64;
  const float log2g = log2f(1.0f - exp2f(-5.0f - (float)h));
  const float gs = exp2f(64.0f * log2g);
  const int tid = threadIdx.x;

  // staging roles (fixed per thread across chunks)
  const int kc0 = tid >> 4;               // k unit 0: row c
  const int kd0 = (tid & 15) * 8;         // k unit: dk offset
  const int kc1 = kc0 + 32;               // k unit 1: row c
  const float dec0 = exp2f((float)(63 - kc0) * log2g);
  const float dec1 = exp2f((float)(63 - kc1) * log2g);
  const int vc0 = tid >> 3;               // v unit: row c
  const int ve0 = (tid & 7) * 8;          // v unit: dv-local offset

  const bf16* kp = kb + (size_t)(b * 4096) * 1024 + h * 128;
  const bf16* vp = vb + (size_t)(b * 4096) * 1024 + h * 128 + dv0;
  bf16* tp = Tb + (size_t)(bh * 64) * 16384;

  const int w = tid >> 6, lane = tid & 63, lr = lane & 15, quad = lane >> 4;
  const int wr = w >> 2, wc = w & 3;      // dk half (64), dv 16-col tile

  f32x4 Sreg[4] = {};                     // S[dk=wr*64+i*16+quad*4+r][dv=wc*16+lr]
  uint4 kr0 = *(const uint4*)&kp[(size_t)kc0 * 1024 + kd0];
  uint4 kr1 = *(const uint4*)&kp[(size_t)kc1 * 1024 + kd0];
  uint4 vr  = *(const uint4*)&vp[(size_t)vc0 * 1024 + ve0];

  for (int n = 0; n < 64; ++n) {
    const int bi = n & 1;
    // write staged regs -> LDS[bi].  Safe vs iter n-2 reads: the single
    // barrier at iter n-1 ordered them before these writes.
    union { uint4 u4; bf16 h8[8]; } t0, t1, tv;
    t0.u4 = kr0; t1.u4 = kr1; tv.u4 = vr;
#pragma unroll
    for (int j = 0; j < 8; ++j) {
      lK[bi][swz72(kd0 + j, kc0)] = (bf16)((float)t0.h8[j] * dec0);
      lK[bi][swz72(kd0 + j, kc1)] = (bf16)((float)t1.h8[j] * dec1);
      lV[bi][swz72(ve0 + j, vc0)] = tv.h8[j];
    }
    __syncthreads();
    // prefetch chunk n+1 (latency hides under MFMA + S-store)
    if (n < 63) {
      const size_t roff = (size_t)(n + 1) * 64 * 1024;
      kr0 = *(const uint4*)&kp[roff + (size_t)kc0 * 1024 + kd0];
      kr1 = *(const uint4*)&kp[roff + (size_t)kc1 * 1024 + kd0];
      vr  = *(const uint4*)&vp[roff + (size_t)vc0 * 1024 + ve0];
    }
    // T-slice: acc[i] = sum_c k~[dk,c] * v[dv,c]
    f32x4 acc[4] = {};
#pragma unroll
    for (int kk = 0; kk < 2; ++kk) {
      bf16x8 bv = *(bf16x8*)&lV[bi][swz72(wc * 16 + lr, kk * 32 + quad * 8)];
#pragma unroll
      for (int i = 0; i < 4; ++i) {
        bf16x8 af =
            *(bf16x8*)&lK[bi][swz72(wr * 64 + i * 16 + lr, kk * 32 + quad * 8)];
        acc[i] = MFMA16(af, bv, acc[i]);
      }
    }
    // write Sprev (exclusive prefix) for chunk n, then update S.
    bf16* tc = tp + (size_t)n * 16384;
#pragma unroll
    for (int i = 0; i < 4; ++i) {
      union { bf16 h4[4]; uint2 u2; } pk;
#pragma unroll
      for (int r = 0; r < 4; ++r) pk.h4[r] = (bf16)Sreg[i][r];
      *(uint2*)&tc[(size_t)(dv0 + wc * 16 + lr) * 128 + wr * 64 + i * 16 +
                   quad * 4] = pk.u2;
      Sreg[i] = gs * Sreg[i] + acc[i];
    }
  }
}

// ---------------------------------------------------------------------------
// Phase C: per-(b,h,chunk) output (round-2 best config):
// P = (q@k^T) * D(mask/decay);  o = P@v + (q * g^(i+1)) @ S_prev
// ---------------------------------------------------------------------------
__global__ __launch_bounds__(256) void chunk_out(
    const bf16* __restrict__ qb, const bf16* __restrict__ kb,
    const bf16* __restrict__ vb, const bf16* __restrict__ Sp,
    bf16* __restrict__ ob) {
  __shared__ bf16 lQ[64 * 136];   // [c][dk]
  __shared__ bf16 lQd[64 * 136];  // [c][dk] * gamma^(c+1)
  __shared__ bf16 lK[64 * 136];   // [c][dk]
  __shared__ bf16 lVt[128 * 72];  // [dv][c] (swizzled)
  __shared__ bf16 lP[64 * 72];    // [ci][cj] masked scores
  const int g = blockIdx.x;
  const int bh = g >> 6, n = g & 63, b = bh >> 3, h = bh & 7;
  const float log2g = log2f(1.0f - exp2f(-5.0f - (float)h));
  const int tid = threadIdx.x;
  const size_t rowbase = (size_t)(b * 4096 + n * 64) * 1024 + h * 128;
  const bf16* qc = qb + rowbase;
  const bf16* kc = kb + rowbase;
  const bf16* vc = vb + rowbase;
#pragma unroll
  for (int s = 0; s < 4; ++s) {
    int u = tid + s * 256;
    int c = u >> 4, d0 = (u & 15) * 8;
    union { uint4 u4; bf16 h8[8]; } qv, vv, qd;
    qv.u4 = *(const uint4*)&qc[(size_t)c * 1024 + d0];
    *(uint4*)&lQ[c * 136 + d0] = qv.u4;
    *(uint4*)&lK[c * 136 + d0] = *(const uint4*)&kc[(size_t)c * 1024 + d0];
    const float dq = exp2f((float)(c + 1) * log2g);
#pragma unroll
    for (int j = 0; j < 8; ++j) qd.h8[j] = (bf16)((float)qv.h8[j] * dq);
    *(uint4*)&lQd[c * 136 + d0] = qd.u4;
    vv.u4 = *(const uint4*)&vc[(size_t)c * 1024 + d0];
#pragma unroll
    for (int j = 0; j < 8; ++j) lVt[swz72(d0 + j, c)] = vv.h8[j];
  }
  __syncthreads();
  const int w = tid >> 6, lane = tid & 63, lr = lane & 15, quad = lane >> 4;

  // --- Step 1: P = q @ k^T; wave w computes columns [w*16, w*16+16) ---
  f32x4 p[4] = {};
#pragma unroll
  for (int kk = 0; kk < 4; ++kk) {
    bf16x8 bfrag = *(bf16x8*)&lK[(w * 16 + lr) * 136 + kk * 32 + quad * 8];
#pragma unroll
    for (int i = 0; i < 4; ++i) {
      bf16x8 afrag = *(bf16x8*)&lQ[(i * 16 + lr) * 136 + kk * 32 + quad * 8];
      p[i] = MFMA16(afrag, bfrag, p[i]);
    }
  }
  // mask + decay, write to lP (bf16)
#pragma unroll
  for (int i = 0; i < 4; ++i) {
#pragma unroll
    for (int r = 0; r < 4; ++r) {
      const int row = i * 16 + quad * 4 + r;
      const int col = w * 16 + lr;
      const int diff = row - col;
      const float val =
          (diff >= 0) ? p[i][r] * exp2f((float)diff * log2g) : 0.0f;
      lP[row * 72 + col] = (bf16)val;
    }
  }
  __syncthreads();

  // --- Step 2: o_intra = P @ v; wave w covers dv in [w*32, w*32+32) ---
  f32x4 oacc[4][2] = {};
#pragma unroll
  for (int j = 0; j < 2; ++j) {
    const int dvt = w * 32 + j * 16;
#pragma unroll
    for (int kk = 0; kk < 2; ++kk) {
      bf16x8 bfrag = *(bf16x8*)&lVt[swz72(dvt + lr, kk * 32 + quad * 8)];
#pragma unroll
      for (int i = 0; i < 4; ++i) {
        bf16x8 afrag = *(bf16x8*)&lP[(i * 16 + lr) * 72 + kk * 32 + quad * 8];
        oacc[i][j] = MFMA16(afrag, bfrag, oacc[i][j]);
      }
    }
  }

  // --- Step 3: o_inter = (q_decayed) @ S_prev ---
  const bf16* sp = Sp + (size_t)g * 16384;
#pragma unroll
  for (int kk = 0; kk < 4; ++kk) {
    bf16x8 aN[4];
#pragma unroll
    for (int i = 0; i < 4; ++i)
      aN[i] = *(bf16x8*)&lQd[(i * 16 + lr) * 136 + kk * 32 + quad * 8];
#pragma unroll
    for (int j = 0; j < 2; ++j) {
      bf16x8 bfrag =
          *(const bf16x8*)&sp[(size_t)(w * 32 + j * 16 + lr) * 128 + kk * 32 + quad * 8];
#pragma unroll
      for (int i = 0; i < 4; ++i) oacc[i][j] = MFMA16(aN[i], bfrag, oacc[i][j]);
    }
  }

  // --- write o chunk ---
  bf16* oc = ob + rowbase;
#pragma unroll
  for (int i = 0; i < 4; ++i)
#pragma unroll
    for (int j = 0; j < 2; ++j)
#pragma unroll
      for (int r = 0; r < 4; ++r) {
        const int row = i * 16 + quad * 4 + r;
        const int col = w * 32 + j * 16 + lr;
        oc[(size_t)row * 1024 + col] = (bf16)oacc[i][j][r];
      }
}

// ---------------------------------------------------------------------------
extern "C" void kernel_launch(void* const* d_in, const int* in_sizes, int n_in,
                              void* d_out, int out_size, void* d_ws,
                              size_t ws_size, hipStream_t stream) {
  const float* X  = (const float*)d_in[0];
  const float* Wq = (const float*)d_in[2];
  const float* Wk = (const float*)d_in[3];
  const float* Wv = (const float*)d_in[4];
  const float* Wo = (const float*)d_in[5];

  char* ws = (char*)d_ws;
  const size_t SZ_QKV = (size_t)8192 * 1024 * sizeof(bf16);  // 16 MiB each
  bf16* qb = (bf16*)(ws);                                    // q,k,v contiguous
  bf16* ob = (bf16*)(ws + 3 * SZ_QKV);
  bf16* Tb = (bf16*)(ws + 4 * SZ_QKV);                       // 32 MiB (Sprev)
  bf16* Wt = (bf16*)(ws + 6 * SZ_QKV);                       // 8 MiB
  bf16* Xb = (bf16*)(ws + 6 * SZ_QKV + (size_t)4 * 1024 * 1024 * sizeof(bf16));
  bf16* kb = qb + (size_t)8192 * 1024;
  bf16* vb = kb + (size_t)8192 * 1024;

  prep<<<5120, 256, 0, stream>>>(X, Wq, Wk, Wv, Wo, Xb, Wt);

  const float qscale = 0.08838834764831845f;  // 128^-0.5
  // fused q/k/v projection: z selects weight + output slice
  gemm_lds<bf16, 1><<<dim3(64, 8, 3), 256, 0, stream>>>(Xb, Wt, qb, qscale);

  // fused chunk_kv + scan: S carried in fp32 registers, T_n never hits HBM.
  chunk_kv_scan<<<32, 512, 0, stream>>>(kb, vb, Tb);

  chunk_out<<<1024, 256, 0, stream>>>(qb, kb, vb, Tb, ob);

  gemm_lds<float, 0><<<dim3(64, 8), 256, 0, stream>>>(
      ob, Wt + (size_t)3 * 1024 * 1024, (float*)d_out, 1.0f);
}

// Round 7
// 228.828 us; speedup vs baseline: 1.3375x; 1.3375x over previous
//
#include <hip/hip_runtime.h>
#include <hip/hip_bf16.h>

typedef __bf16 bf16;
typedef __bf16 bf16x8 __attribute__((ext_vector_type(8)));
typedef float f32x4 __attribute__((ext_vector_type(4)));

#define MFMA16(a, b, c) __builtin_amdgcn_mfma_f32_16x16x32_bf16((a), (b), (c), 0, 0, 0)

// Problem: B=2, L=4096, D=1024, H=8, Hd=128, CHUNK=64, NCHUNK=64
// gamma_h = 1 - 2^(-5-h).  Inputs fp32, OUTPUT fp32.
//
// SESSION LEDGER (best measured = THIS config, 230.55 us):
//  - GEMM deep pipelines: 3-buf 2-phase (-7%), 256^2 8-phase port (-11%) —
//    axis CLOSED; 128^2 2-barrier structure at ~858 TF is the keeper.
//  - QKV 3-launch split: +15 us (lost overlap) — keep z=3 fusion.
//  - chunk_kv+scan fusion (S in regs): 32 blocks = 12.5% of CUs, serial
//    64-iter chain -> 111 us vs ~34 us split.  Axis CLOSED.
//  - Census: harness re-poison fills ~80 us (256 MiB fill = 41 us @ 82% HBM
//    peak) are inside the timed stream and not controllable kernel-side.

// async 16B global->LDS (gfx950). LDS dest is wave-uniform base + lane*16.
__device__ __forceinline__ void g2l16(const bf16* g, bf16* l) {
  __builtin_amdgcn_global_load_lds(
      (const __attribute__((address_space(1))) void*)g,
      (__attribute__((address_space(3))) void*)l, 16, 0, 0);
}

// Transpose-safe LDS index, stride-72 rows (bf16).
__device__ __forceinline__ int swz72(int row, int c) {
  return row * 72 + (c & 7) + ((((c >> 3) ^ (row >> 3)) & 7) << 3);
}

// ---------------------------------------------------------------------------
// prep: fused {fp32->bf16 convert of X} + {transpose+cvt of the 4 weights}.
// ---------------------------------------------------------------------------
__global__ __launch_bounds__(256) void prep(
    const float* __restrict__ X, const float* __restrict__ Wq,
    const float* __restrict__ Wk, const float* __restrict__ Wv,
    const float* __restrict__ Wo, bf16* __restrict__ Xb,
    bf16* __restrict__ Wt) {
  __shared__ bf16 t[64 * 72];
  const int tid = threadIdx.x;
  if (blockIdx.x < 4096) {
    const size_t i = ((size_t)blockIdx.x * 256 + tid) * 8;
    float4 a = *(const float4*)&X[i];
    float4 b = *(const float4*)&X[i + 4];
    union { bf16 h[8]; uint4 u; } p;
    p.h[0] = (bf16)a.x; p.h[1] = (bf16)a.y; p.h[2] = (bf16)a.z; p.h[3] = (bf16)a.w;
    p.h[4] = (bf16)b.x; p.h[5] = (bf16)b.y; p.h[6] = (bf16)b.z; p.h[7] = (bf16)b.w;
    *(uint4*)&Xb[i] = p.u;
    return;
  }
  const int bid2 = blockIdx.x - 4096;          // 0..1023
  const int bx = bid2 & 15, by = (bid2 >> 4) & 15, bz = bid2 >> 8;
  const float* src = (bz == 0) ? Wq : (bz == 1) ? Wk : (bz == 2) ? Wv : Wo;
  bf16* dst = Wt + (size_t)bz * 1024 * 1024;
  const int k0 = bx * 64, n0 = by * 64;
#pragma unroll
  for (int s = 0; s < 4; ++s) {
    int u = tid + s * 256;          // 0..1023
    int r = u >> 4, c4 = (u & 15) * 4;
    float4 f = *(const float4*)&src[(size_t)(k0 + r) * 1024 + n0 + c4];
    t[r * 72 + c4 + 0] = (bf16)f.x;
    t[r * 72 + c4 + 1] = (bf16)f.y;
    t[r * 72 + c4 + 2] = (bf16)f.z;
    t[r * 72 + c4 + 3] = (bf16)f.w;
  }
  __syncthreads();
#pragma unroll
  for (int s = 0; s < 2; ++s) {
    int u = tid + s * 256;
    int r = u >> 3, cc = u & 7;     // output row n0+r, k-chunk cc
    union { bf16 h[8]; uint4 u4; } pk;
#pragma unroll
    for (int j = 0; j < 8; ++j) pk.h[j] = t[(cc * 8 + j) * 72 + r];
    *(uint4*)&dst[(size_t)(n0 + r) * 1024 + k0 + cc * 8] = pk.u4;
  }
}

// ---------------------------------------------------------------------------
// GEMM: C = alpha * (A @ Bt^T).  A: M x 1024 bf16 row-major,
// Bt: 1024 x 1024 bf16 = B^T row-major, C: M x 1024 (TC = bf16 or fp32).
// 128x128 tile, BK=64, 4 waves. global_load_lds(16B) staging with XOR-swizzle:
// logical 16B-chunk c of row r lives at physical chunk c^(r&7) (unpadded rows,
// stride 64 bf16) -> fragment ds_read_b128 spreads across all 32 banks 2-way.
// If QKV!=0: gridDim.z selects Wt slice z and output slice z (q gets alpha).
// ---------------------------------------------------------------------------
template <typename TC, int QKV>
__global__ __launch_bounds__(256) void gemm_lds(
    const bf16* __restrict__ A, const bf16* __restrict__ Bt,
    TC* __restrict__ C, float alpha) {
  __shared__ bf16 lA[128 * 64];
  __shared__ bf16 lB[128 * 64];
  const int m0 = blockIdx.x * 128, n0 = blockIdx.y * 128;
  if (QKV) {
    Bt += (size_t)blockIdx.z * 1024 * 1024;
    C += (size_t)blockIdx.z * 8192 * 1024;
    if (blockIdx.z != 0) alpha = 1.0f;
  }
  const int tid = threadIdx.x;
  const int w = tid >> 6, lane = tid & 63, lr = lane & 15, quad = lane >> 4;
  const int wm = w >> 1, wn = w & 1;

  // staging map: wave w stages rows [w*32, w*32+32) in 4 issues of 8 rows.
  const int srow = w * 32 + (lane >> 3);              // row for issue 0
  const int clog = (lane & 7) ^ ((lane >> 3) & 7);    // swizzled 16B chunk
  const bf16* gA = A + (size_t)(m0 + srow) * 1024 + clog * 8;
  const bf16* gB = Bt + (size_t)(n0 + srow) * 1024 + clog * 8;

  f32x4 acc[4][4] = {};

  for (int it = 0; it < 16; ++it) {
    const int k0 = it * 64;
#pragma unroll
    for (int is = 0; is < 4; ++is) {
      g2l16(gA + (size_t)is * 8 * 1024 + k0, &lA[(w * 32 + is * 8) * 64]);
      g2l16(gB + (size_t)is * 8 * 1024 + k0, &lB[(w * 32 + is * 8) * 64]);
    }
    __syncthreads();
#pragma unroll
    for (int kk = 0; kk < 2; ++kk) {
      bf16x8 af[4], bfv[4];
#pragma unroll
      for (int i = 0; i < 4; ++i) {
        const int m = wm * 64 + i * 16 + lr;
        af[i] = *(bf16x8*)&lA[m * 64 + (((kk * 4 + quad) ^ (lr & 7)) * 8)];
      }
#pragma unroll
      for (int j = 0; j < 4; ++j) {
        const int n = wn * 64 + j * 16 + lr;
        bfv[j] = *(bf16x8*)&lB[n * 64 + (((kk * 4 + quad) ^ (lr & 7)) * 8)];
      }
#pragma unroll
      for (int i = 0; i < 4; ++i)
#pragma unroll
        for (int j = 0; j < 4; ++j)
          acc[i][j] = MFMA16(af[i], bfv[j], acc[i][j]);
    }
    __syncthreads();
  }
  // Epilogue: D layout col=lane&15, row=quad*4+r
#pragma unroll
  for (int i = 0; i < 4; ++i) {
#pragma unroll
    for (int j = 0; j < 4; ++j) {
      const int row = m0 + wm * 64 + i * 16 + quad * 4;
      const int col = n0 + wn * 64 + j * 16 + lr;
#pragma unroll
      for (int r = 0; r < 4; ++r)
        C[(size_t)(row + r) * 1024 + col] = (TC)(acc[i][j][r] * alpha);
    }
  }
}

// ---------------------------------------------------------------------------
// Phase A: per-(b,h,chunk) T^T[dv][dk] = sum_c k[c][dk]*g^(63-c)*v[c][dv]
// grid = 1024 (bh*64+n), bf16 output at Tb + g*16384, layout [dv][dk].
// ---------------------------------------------------------------------------
__global__ __launch_bounds__(256) void chunk_kv(
    const bf16* __restrict__ kb, const bf16* __restrict__ vb,
    bf16* __restrict__ Tb) {
  __shared__ bf16 lK[128 * 72];  // [dk][c] with decay folded in (swizzled)
  __shared__ bf16 lV[128 * 72];  // [dv][c] (swizzled)
  const int g = blockIdx.x;
  const int bh = g >> 6, n = g & 63, b = bh >> 3, h = bh & 7;
  const float log2g = log2f(1.0f - exp2f(-5.0f - (float)h));
  const int tid = threadIdx.x;
  const size_t rowbase = (size_t)(b * 4096 + n * 64) * 1024 + h * 128;
  const bf16* kc = kb + rowbase;
  const bf16* vc = vb + rowbase;
#pragma unroll
  for (int s = 0; s < 4; ++s) {
    int u = tid + s * 256;
    int c = u >> 4, d0 = (u & 15) * 8;
    union { uint4 u4; bf16 h8[8]; } kv, vv;
    kv.u4 = *(const uint4*)&kc[(size_t)c * 1024 + d0];
    vv.u4 = *(const uint4*)&vc[(size_t)c * 1024 + d0];
    const float dec = exp2f((float)(63 - c) * log2g);
#pragma unroll
    for (int j = 0; j < 8; ++j) {
      lK[swz72(d0 + j, c)] = (bf16)((float)kv.h8[j] * dec);
      lV[swz72(d0 + j, c)] = vv.h8[j];
    }
  }
  __syncthreads();
  const int w = tid >> 6, lane = tid & 63, lr = lane & 15, quad = lane >> 4;
  const int wm = w >> 1, wn = w & 1;
  f32x4 acc[4][4] = {};
#pragma unroll
  for (int kk = 0; kk < 2; ++kk) {
    bf16x8 af[4], bv[4];
#pragma unroll
    for (int i = 0; i < 4; ++i)
      af[i] = *(bf16x8*)&lK[swz72(wm * 64 + i * 16 + lr, kk * 32 + quad * 8)];
#pragma unroll
    for (int j = 0; j < 4; ++j)
      bv[j] = *(bf16x8*)&lV[swz72(wn * 64 + j * 16 + lr, kk * 32 + quad * 8)];
#pragma unroll
    for (int i = 0; i < 4; ++i)
#pragma unroll
      for (int j = 0; j < 4; ++j)
        acc[i][j] = MFMA16(af[i], bv[j], acc[i][j]);
  }
  bf16* tchunk = Tb + (size_t)g * 16384;
#pragma unroll
  for (int i = 0; i < 4; ++i) {
#pragma unroll
    for (int j = 0; j < 4; ++j) {
      const int dk = wm * 64 + i * 16 + quad * 4;  // row of T (r advances dk)
      const int dv = wn * 64 + j * 16 + lr;        // col of T
      union { bf16 h4[4]; uint2 u2; } pk;
#pragma unroll
      for (int r = 0; r < 4; ++r) pk.h4[r] = (bf16)acc[i][j][r];
      *(uint2*)&tchunk[(size_t)dv * 128 + dk] = pk.u2;  // transposed store
    }
  }
}

// ---------------------------------------------------------------------------
// Phase B: in-place exclusive prefix scan over chunks:
// slot n <- S_{n-1};  S <- gamma^64 * S + T_n.  fp32 accumulators in register.
// Vectorized x8: grid 128 (bh*8+seg), thread owns 8 consecutive bf16.
// ---------------------------------------------------------------------------
__global__ __launch_bounds__(256) void scan_state(bf16* __restrict__ Tb) {
  const int blk = blockIdx.x;               // 0..127
  const int bh = blk >> 3, seg = blk & 7, h = bh & 7;
  const float gs = exp2f(64.0f * log2f(1.0f - exp2f(-5.0f - (float)h)));
  const size_t base = (size_t)bh * 64 * 16384 + (size_t)seg * 2048 +
                      (size_t)threadIdx.x * 8;
  float S[8] = {0.f, 0.f, 0.f, 0.f, 0.f, 0.f, 0.f, 0.f};
#pragma unroll 4
  for (int n = 0; n < 64; ++n) {
    const size_t a = base + (size_t)n * 16384;
    union { uint4 u4; bf16 h8[8]; } in, out;
    in.u4 = *(const uint4*)&Tb[a];
#pragma unroll
    for (int e = 0; e < 8; ++e) {
      out.h8[e] = (bf16)S[e];
      S[e] = gs * S[e] + (float)in.h8[e];
    }
    *(uint4*)&Tb[a] = out.u4;
  }
}

// ---------------------------------------------------------------------------
// Phase C: per-(b,h,chunk) output:
// P = (q@k^T) * D(mask/decay);  o = P@v + (q * g^(i+1)) @ S_prev
// lVt swizzled; lQd = decay-folded Q copy so step 3 is pure ds_read + MFMA.
// ---------------------------------------------------------------------------
__global__ __launch_bounds__(256) void chunk_out(
    const bf16* __restrict__ qb, const bf16* __restrict__ kb,
    const bf16* __restrict__ vb, const bf16* __restrict__ Sp,
    bf16* __restrict__ ob) {
  __shared__ bf16 lQ[64 * 136];   // [c][dk]
  __shared__ bf16 lQd[64 * 136];  // [c][dk] * gamma^(c+1)
  __shared__ bf16 lK[64 * 136];   // [c][dk]
  __shared__ bf16 lVt[128 * 72];  // [dv][c] (swizzled)
  __shared__ bf16 lP[64 * 72];    // [ci][cj] masked scores
  const int g = blockIdx.x;
  const int bh = g >> 6, n = g & 63, b = bh >> 3, h = bh & 7;
  const float log2g = log2f(1.0f - exp2f(-5.0f - (float)h));
  const int tid = threadIdx.x;
  const size_t rowbase = (size_t)(b * 4096 + n * 64) * 1024 + h * 128;
  const bf16* qc = qb + rowbase;
  const bf16* kc = kb + rowbase;
  const bf16* vc = vb + rowbase;
#pragma unroll
  for (int s = 0; s < 4; ++s) {
    int u = tid + s * 256;
    int c = u >> 4, d0 = (u & 15) * 8;
    union { uint4 u4; bf16 h8[8]; } qv, vv, qd;
    qv.u4 = *(const uint4*)&qc[(size_t)c * 1024 + d0];
    *(uint4*)&lQ[c * 136 + d0] = qv.u4;
    *(uint4*)&lK[c * 136 + d0] = *(const uint4*)&kc[(size_t)c * 1024 + d0];
    const float dq = exp2f((float)(c + 1) * log2g);
#pragma unroll
    for (int j = 0; j < 8; ++j) qd.h8[j] = (bf16)((float)qv.h8[j] * dq);
    *(uint4*)&lQd[c * 136 + d0] = qd.u4;
    vv.u4 = *(const uint4*)&vc[(size_t)c * 1024 + d0];
#pragma unroll
    for (int j = 0; j < 8; ++j) lVt[swz72(d0 + j, c)] = vv.h8[j];
  }
  __syncthreads();
  const int w = tid >> 6, lane = tid & 63, lr = lane & 15, quad = lane >> 4;

  // --- Step 1: P = q @ k^T; wave w computes columns [w*16, w*16+16) ---
  f32x4 p[4] = {};
#pragma unroll
  for (int kk = 0; kk < 4; ++kk) {
    bf16x8 bfrag = *(bf16x8*)&lK[(w * 16 + lr) * 136 + kk * 32 + quad * 8];
#pragma unroll
    for (int i = 0; i < 4; ++i) {
      bf16x8 afrag = *(bf16x8*)&lQ[(i * 16 + lr) * 136 + kk * 32 + quad * 8];
      p[i] = MFMA16(afrag, bfrag, p[i]);
    }
  }
  // mask + decay, write to lP (bf16)
#pragma unroll
  for (int i = 0; i < 4; ++i) {
#pragma unroll
    for (int r = 0; r < 4; ++r) {
      const int row = i * 16 + quad * 4 + r;
      const int col = w * 16 + lr;
      const int diff = row - col;
      const float val =
          (diff >= 0) ? p[i][r] * exp2f((float)diff * log2g) : 0.0f;
      lP[row * 72 + col] = (bf16)val;
    }
  }
  __syncthreads();

  // --- Step 2: o_intra = P @ v; wave w covers dv in [w*32, w*32+32) ---
  f32x4 oacc[4][2] = {};
#pragma unroll
  for (int j = 0; j < 2; ++j) {
    const int dvt = w * 32 + j * 16;
#pragma unroll
    for (int kk = 0; kk < 2; ++kk) {
      bf16x8 bfrag = *(bf16x8*)&lVt[swz72(dvt + lr, kk * 32 + quad * 8)];
#pragma unroll
      for (int i = 0; i < 4; ++i) {
        bf16x8 afrag = *(bf16x8*)&lP[(i * 16 + lr) * 72 + kk * 32 + quad * 8];
        oacc[i][j] = MFMA16(afrag, bfrag, oacc[i][j]);
      }
    }
  }

  // --- Step 3: o_inter = (q_decayed) @ S_prev ---
  const bf16* sp = Sp + (size_t)g * 16384;
#pragma unroll
  for (int kk = 0; kk < 4; ++kk) {
    bf16x8 aN[4];
#pragma unroll
    for (int i = 0; i < 4; ++i)
      aN[i] = *(bf16x8*)&lQd[(i * 16 + lr) * 136 + kk * 32 + quad * 8];
#pragma unroll
    for (int j = 0; j < 2; ++j) {
      bf16x8 bfrag =
          *(const bf16x8*)&sp[(size_t)(w * 32 + j * 16 + lr) * 128 + kk * 32 + quad * 8];
#pragma unroll
      for (int i = 0; i < 4; ++i) oacc[i][j] = MFMA16(aN[i], bfrag, oacc[i][j]);
    }
  }

  // --- write o chunk ---
  bf16* oc = ob + rowbase;
#pragma unroll
  for (int i = 0; i < 4; ++i)
#pragma unroll
    for (int j = 0; j < 2; ++j)
#pragma unroll
      for (int r = 0; r < 4; ++r) {
        const int row = i * 16 + quad * 4 + r;
        const int col = w * 32 + j * 16 + lr;
        oc[(size_t)row * 1024 + col] = (bf16)oacc[i][j][r];
      }
}

// ---------------------------------------------------------------------------
extern "C" void kernel_launch(void* const* d_in, const int* in_sizes, int n_in,
                              void* d_out, int out_size, void* d_ws,
                              size_t ws_size, hipStream_t stream) {
  const float* X  = (const float*)d_in[0];
  const float* Wq = (const float*)d_in[2];
  const float* Wk = (const float*)d_in[3];
  const float* Wv = (const float*)d_in[4];
  const float* Wo = (const float*)d_in[5];

  char* ws = (char*)d_ws;
  const size_t SZ_QKV = (size_t)8192 * 1024 * sizeof(bf16);  // 16 MiB each
  bf16* qb = (bf16*)(ws);                                    // q,k,v contiguous
  bf16* ob = (bf16*)(ws + 3 * SZ_QKV);
  bf16* Tb = (bf16*)(ws + 4 * SZ_QKV);                       // 32 MiB
  bf16* Wt = (bf16*)(ws + 6 * SZ_QKV);                       // 8 MiB
  bf16* Xb = (bf16*)(ws + 6 * SZ_QKV + (size_t)4 * 1024 * 1024 * sizeof(bf16));
  bf16* kb = qb + (size_t)8192 * 1024;
  bf16* vb = kb + (size_t)8192 * 1024;

  prep<<<5120, 256, 0, stream>>>(X, Wq, Wk, Wv, Wo, Xb, Wt);

  const float qscale = 0.08838834764831845f;  // 128^-0.5
  // fused q/k/v projection: z selects weight + output slice
  gemm_lds<bf16, 1><<<dim3(64, 8, 3), 256, 0, stream>>>(Xb, Wt, qb, qscale);

  chunk_kv<<<1024, 256, 0, stream>>>(kb, vb, Tb);
  scan_state<<<128, 256, 0, stream>>>(Tb);
  chunk_out<<<1024, 256, 0, stream>>>(qb, kb, vb, Tb, ob);

  gemm_lds<float, 0><<<dim3(64, 8), 256, 0, stream>>>(
      ob, Wt + (size_t)3 * 1024 * 1024, (float*)d_out, 1.0f);
}